// Round 5
// baseline (15.434 us; speedup 1.0000x reference)
//
#include <hip/hip_runtime.h>

// Problem constants (from reference)
#define O_NUM 256
#define IN_NUM 768
#define NS 32            // B*R = 8*4 samples
#define L0 128
#define L1 22
#define L2 4
#define QC 32            // cells per K1 block (L0/4)
// Padded LDS row strides (odd -> conflict-free for sample-strided access)
#define Y0S 133          // >= L1*6 = 132
#define Y1S 25           // >= L2*6 = 24
#define Y2S 7            // >= 6

// (tanh(w)+1)/2 == sigmoid(2w) == 1/(1 + 2^(-2*log2(e)*w))
__device__ __forceinline__ float fast_sig2(float w) {
    float e = __builtin_amdgcn_exp2f(w * -2.8853900817779268f);
    return __builtin_amdgcn_rcpf(1.0f + e);
}
__device__ __forceinline__ float4 sig4(float4 q) {
    float4 r = { fast_sig2(q.x), fast_sig2(q.y), fast_sig2(q.z), fast_sig2(q.w) };
    return r;
}

// 6-level LUT tree with weights pre-split: we[j]=w[2j], dd[j]=w[2j+1]-w[2j].
// Level 0 is 32 fma; levels 1..5 standard. Keeps only 64 weight VGPRs live.
__device__ __forceinline__ float lut6_wd(const float* __restrict__ we,
                                         const float* __restrict__ dd,
                                         const float* __restrict__ b) {
    float v[32];
#pragma unroll
    for (int j = 0; j < 32; ++j)
        v[j] = fmaf(b[0], dd[j], we[j]);
#pragma unroll
    for (int lvl = 1; lvl < 6; ++lvl) {
        const int n = 32 >> lvl;
#pragma unroll
        for (int j = 0; j < n; ++j)
            v[j] = fmaf(b[lvl], v[2 * j + 1] - v[2 * j], v[2 * j]);
    }
    return v[0];
}

// Load a 64-float LDS row into we/dd form via ds_read_b128.
__device__ __forceinline__ void load_row_wd(const float* __restrict__ src,
                                            float* __restrict__ we, float* __restrict__ dd) {
    const float4* p = (const float4*)src;   // rows are 256B-aligned
#pragma unroll
    for (int k = 0; k < 16; ++k) {
        float4 q = p[k];
        we[2 * k]     = q.x; dd[2 * k]     = q.y - q.x;
        we[2 * k + 1] = q.z; dd[2 * k + 1] = q.w - q.z;
    }
}

// ---------------- K1: layer 0 ----------------
// grid = O_NUM*4 blocks: (o, quarter h). 256 threads, 4 blocks/CU.
__global__ __launch_bounds__(256, 4) void lut_k1(
    const float* __restrict__ x,    // [NS][IN_NUM]
    const float* __restrict__ w0,   // [O_NUM][L0][64]
    float* __restrict__ y0g)        // [O_NUM][NS][L0]
{
    const int o = blockIdx.x >> 2;
    const int h = blockIdx.x & 3;
    const int tid = threadIdx.x;

    __shared__ float4 sw0[QC * 16];  // 8 KB, XOR-swizzled rows

    // Stage QC rows of w0: 512 float4, coalesced, sig2 once per weight.
    {
        const float4* g = (const float4*)(w0 + ((size_t)o * L0 + h * QC) * 64);
#pragma unroll
        for (int r = 0; r < 2; ++r) {
            int idx = r * 256 + tid;            // 0..511
            float4 t = sig4(g[idx]);
            int lw = idx >> 4, kw = idx & 15;
            sw0[lw * 16 + (kw ^ (lw & 15))] = t;
        }
    }
    __syncthreads();

    const int l  = tid & 31;        // local cell
    const int sg = tid >> 5;        // sample group 0..7 (4 samples each)
    const int L  = h * QC + l;      // global cell

    float we[32], dd[32];
    {
        const int base = l * 16, sw = l & 15;
#pragma unroll
        for (int k = 0; k < 16; ++k) {
            float4 q = sw0[base + (k ^ sw)];
            we[2 * k]     = q.x; dd[2 * k]     = q.y - q.x;
            we[2 * k + 1] = q.z; dd[2 * k + 1] = q.w - q.z;
        }
    }

#pragma unroll
    for (int i = 0; i < 4; ++i) {
        const int s = sg * 4 + i;
        const float2* xb = (const float2*)(x + (size_t)s * IN_NUM + L * 6);  // 8B-aligned
        float2 b01 = xb[0], b23 = xb[1], b45 = xb[2];
        float b[6] = { b01.x, b01.y, b23.x, b23.y, b45.x, b45.y };
        y0g[((size_t)o * NS + s) * L0 + L] = lut6_wd(we, dd, b);
    }
}

// ---------------- K2: layers 1-3 ----------------
// grid = O_NUM blocks, 256 threads.
__global__ __launch_bounds__(256) void lut_k2(
    const float* __restrict__ y0g,  // [O_NUM][NS][L0]
    const float* __restrict__ w1,   // [O_NUM][L1][64]
    const float* __restrict__ w2,   // [O_NUM][L2][64]
    const float* __restrict__ w3,   // [O_NUM][1][64]
    float* __restrict__ out)        // [NS][O_NUM]
{
    const int o = blockIdx.x;
    const int tid = threadIdx.x;

    __shared__ float y0[NS * Y0S];   // ~17 KB
    __shared__ float wq1[L1 * 64];   // 5.5 KB
    __shared__ float wq2[L2 * 64];   // 1 KB
    __shared__ float wq3[64];
    __shared__ float y1[NS * Y1S];   // ~3.1 KB
    __shared__ float y2[NS * Y2S];   // ~0.9 KB

    // Stage y0 slice: 1024 float4, coalesced, into padded rows.
    {
        const float4* gy = (const float4*)(y0g + (size_t)o * (NS * L0));
#pragma unroll
        for (int r = 0; r < 4; ++r) {
            int idx = r * 256 + tid;            // 0..1023
            float4 q = gy[idx];
            int s = idx >> 5, k = (idx & 31) * 4;
            float* dst = &y0[s * Y0S + k];
            dst[0] = q.x; dst[1] = q.y; dst[2] = q.z; dst[3] = q.w;
        }
    }
    // Transform w1/w2/w3 into LDS.
    {
        const float4* gw = (const float4*)(w1 + (size_t)o * (L1 * 64));
        ((float4*)wq1)[tid] = sig4(gw[tid]);                       // 0..255
        if (tid < 96) ((float4*)wq1)[256 + tid] = sig4(gw[256 + tid]);
    }
    if (tid >= 96 && tid < 160) {
        int i = tid - 96;
        ((float4*)wq2)[i] = sig4(((const float4*)(w2 + (size_t)o * (L2 * 64)))[i]);
    }
    if (tid >= 160 && tid < 176) {
        int i = tid - 160;
        ((float4*)wq3)[i] = sig4(((const float4*)(w3 + (size_t)o * 64))[i]);
    }
    // Zero pad bit-slots (pad bit = 0 selects branch 0, matching jnp.pad).
    if (tid < NS * 4) {                       // y0 cols 128..131
        int s = tid >> 2;
        y0[s * Y0S + L0 + (tid & 3)] = 0.0f;
    }
    if (tid < NS * 2) {                       // y1 cols 22..23
        int s = tid >> 1;
        y1[s * Y1S + L1 + (tid & 1)] = 0.0f;
    }
    if (tid >= 64 && tid < 64 + NS * 2) {     // y2 cols 4..5
        int t = tid - 64; int s = t >> 1;
        y2[s * Y2S + L2 + (t & 1)] = 0.0f;
    }
    __syncthreads();

    // Layer 1: 32 x 22 = 704 tasks, sample-fast (weight rows wave-broadcast).
    for (int t = tid; t < NS * L1; t += 256) {
        const int s = t & 31;
        const int c = t >> 5;
        float we[32], dd[32];
        load_row_wd(&wq1[c * 64], we, dd);
        float b[6];
#pragma unroll
        for (int j = 0; j < 6; ++j) b[j] = y0[s * Y0S + c * 6 + j];
        y1[s * Y1S + c] = lut6_wd(we, dd, b);
    }
    __syncthreads();

    // Layer 2: 32 x 4 = 128 tasks.
    if (tid < NS * L2) {
        const int s = tid & 31;
        const int c = tid >> 5;
        float we[32], dd[32];
        load_row_wd(&wq2[c * 64], we, dd);
        float b[6];
#pragma unroll
        for (int j = 0; j < 6; ++j) b[j] = y1[s * Y1S + c * 6 + j];
        y2[s * Y2S + c] = lut6_wd(we, dd, b);
    }
    __syncthreads();

    // Layer 3: one thread per sample.
    if (tid < NS) {
        const int s = tid;
        float we[32], dd[32];
        load_row_wd(wq3, we, dd);
        float b[6];
#pragma unroll
        for (int j = 0; j < 6; ++j) b[j] = y2[s * Y2S + j];
        out[(size_t)s * O_NUM + o] = lut6_wd(we, dd, b);
    }
}

extern "C" void kernel_launch(void* const* d_in, const int* in_sizes, int n_in,
                              void* d_out, int out_size, void* d_ws, size_t ws_size,
                              hipStream_t stream) {
    const float* x  = (const float*)d_in[0];
    const float* w0 = (const float*)d_in[1];
    const float* w1 = (const float*)d_in[2];
    const float* w2 = (const float*)d_in[3];
    const float* w3 = (const float*)d_in[4];
    float* out = (float*)d_out;
    float* y0g = (float*)d_ws;   // O_NUM*NS*L0 floats = 4 MB

    lut_k1<<<dim3(O_NUM * 4), dim3(256), 0, stream>>>(x, w0, y0g);
    lut_k2<<<dim3(O_NUM), dim3(256), 0, stream>>>(y0g, w1, w2, w3, out);
}

// Round 6
// 12.651 us; speedup vs baseline: 1.2200x; 1.2200x over previous
//
#include <hip/hip_runtime.h>

// Problem constants (from reference)
#define O_NUM 256
#define IN_NUM 768
#define NS 32            // B*R = 8*4 samples total
#define SPB 16           // samples per block (sample-split: 2 blocks per o)
#define L0 128
#define L1 22
#define L2 4
// Padded LDS row strides (odd -> conflict-free for sample-strided access)
#define Y0S 133          // >= L1*6 = 132
#define Y1S 25           // >= L2*6 = 24
#define Y2S 7            // >= 6

// (tanh(w)+1)/2 == sigmoid(2w) == 1/(1 + 2^(-2*log2(e)*w))
__device__ __forceinline__ float fast_sig2(float w) {
    float e = __builtin_amdgcn_exp2f(w * -2.8853900817779268f);
    return __builtin_amdgcn_rcpf(1.0f + e);
}
__device__ __forceinline__ float4 sig4(float4 q) {
    float4 r = { fast_sig2(q.x), fast_sig2(q.y), fast_sig2(q.z), fast_sig2(q.w) };
    return r;
}

// 6-level LUT tree, weights pre-split: we[j]=w[2j], dd[j]=w[2j+1]-w[2j].
__device__ __forceinline__ float lut6_wd(const float* __restrict__ we,
                                         const float* __restrict__ dd,
                                         const float* __restrict__ b) {
    float v[32];
#pragma unroll
    for (int j = 0; j < 32; ++j)
        v[j] = fmaf(b[0], dd[j], we[j]);
#pragma unroll
    for (int lvl = 1; lvl < 6; ++lvl) {
        const int n = 32 >> lvl;
#pragma unroll
        for (int j = 0; j < n; ++j)
            v[j] = fmaf(b[lvl], v[2 * j + 1] - v[2 * j], v[2 * j]);
    }
    return v[0];
}

// Load a 64-float LDS row into we/dd form via ds_read_b128.
__device__ __forceinline__ void load_row_wd(const float* __restrict__ src,
                                            float* __restrict__ we, float* __restrict__ dd) {
    const float4* p = (const float4*)src;   // rows are 256B-aligned
#pragma unroll
    for (int k = 0; k < 16; ++k) {
        float4 q = p[k];
        we[2 * k]     = q.x; dd[2 * k]     = q.y - q.x;
        we[2 * k + 1] = q.z; dd[2 * k + 1] = q.w - q.z;
    }
}

// One kernel, grid = 512 blocks = (o, sample-half). 2 blocks/CU, 16 waves/CU:
// one block's staging + barriers overlap the other's compute.
__global__ __launch_bounds__(512) void lut_quant_fc_kernel(
    const float* __restrict__ x,    // [NS][IN_NUM]
    const float* __restrict__ w0,   // [O_NUM][L0][64]
    const float* __restrict__ w1,   // [O_NUM][L1][64]
    const float* __restrict__ w2,   // [O_NUM][L2][64]
    const float* __restrict__ w3,   // [O_NUM][1][64]
    float* __restrict__ out)        // [NS][O_NUM]
{
    const int o  = blockIdx.x >> 1;   // adjacent blocks share o -> L2 reuse of w
    const int sh = blockIdx.x & 1;    // sample half: samples sh*16 .. sh*16+15
    const int tid = threadIdx.x;

    __shared__ float4 sw0[L0 * 16];  // 32 KB, XOR-swizzled transformed w0 rows
    __shared__ float wq1[L1 * 64];   // 5.5 KB
    __shared__ float wq2[L2 * 64];   // 1 KB
    __shared__ float wq3[64];
    __shared__ float y0[SPB * Y0S];  // 8.5 KB
    __shared__ float y1[SPB * Y1S];  // 1.6 KB
    __shared__ float y2[SPB * Y2S];  // 0.5 KB

    // ---- Stage w0: coalesced float4, sig2 once per weight, swizzled store ----
    {
        const float4* g = (const float4*)(w0 + (size_t)o * (L0 * 64));
#pragma unroll
        for (int r = 0; r < 4; ++r) {
            int idx = r * 512 + tid;            // 0..2047, coalesced
            float4 t = sig4(g[idx]);
            int lw = idx >> 4, kw = idx & 15;
            sw0[lw * 16 + (kw ^ (lw & 15))] = t;
        }
    }
    // ---- Stage w1/w2/w3 ----
    if (tid < 352) {                                   // wq1: 352 float4
        ((float4*)wq1)[tid] = sig4(((const float4*)(w1 + (size_t)o * (L1 * 64)))[tid]);
    } else if (tid < 416) {                            // wq2: 64 float4
        int i = tid - 352;
        ((float4*)wq2)[i] = sig4(((const float4*)(w2 + (size_t)o * (L2 * 64)))[i]);
    } else if (tid < 432) {                            // wq3: 16 float4
        int i = tid - 416;
        ((float4*)wq3)[i] = sig4(((const float4*)(w3 + (size_t)o * 64))[i]);
    }
    // ---- Zero pad bit-slots (pad bit = 0 selects branch 0, matching jnp.pad) ----
    if (tid < SPB * 4) {                               // y0 cols 128..131
        int s = tid >> 2;
        y0[s * Y0S + L0 + (tid & 3)] = 0.0f;
    }
    if (tid < SPB * 2) {                               // y1 cols 22..23
        int s = tid >> 1;
        y1[s * Y1S + L1 + (tid & 1)] = 0.0f;
    }
    if (tid >= 64 && tid < 64 + SPB * 2) {             // y2 cols 4..5
        int t = tid - 64; int s = t >> 1;
        y2[s * Y2S + L2 + (t & 1)] = 0.0f;
    }
    __syncthreads();

    // ---- Layer 0: thread = (cell l, sample-group sg of 4) ----
    const int l  = tid & 127;
    const int sg = tid >> 7;          // 0..3

    float we[32], dd[32];
    {
        const int base = l * 16, sw = l & 15;
#pragma unroll
        for (int k = 0; k < 16; ++k) {
            float4 q = sw0[base + (k ^ sw)];
            we[2 * k]     = q.x; dd[2 * k]     = q.y - q.x;
            we[2 * k + 1] = q.z; dd[2 * k + 1] = q.w - q.z;
        }
    }
#pragma unroll
    for (int i = 0; i < 4; ++i) {
        const int sl = sg * 4 + i;                    // local sample 0..15
        const int s  = sh * SPB + sl;                 // global sample
        const float2* xb = (const float2*)(x + (size_t)s * IN_NUM + l * 6);  // 8B-aligned
        float2 b01 = xb[0], b23 = xb[1], b45 = xb[2];
        float b[6] = { b01.x, b01.y, b23.x, b23.y, b45.x, b45.y };
        y0[sl * Y0S + l] = lut6_wd(we, dd, b);
    }
    __syncthreads();

    // ---- Layer 1: 16 x 22 = 352 tasks, one pass ----
    if (tid < SPB * L1) {
        const int s = tid & 15;
        const int c = tid >> 4;
        float we1[32], dd1[32];
        load_row_wd(&wq1[c * 64], we1, dd1);
        float b[6];
#pragma unroll
        for (int j = 0; j < 6; ++j) b[j] = y0[s * Y0S + c * 6 + j];
        y1[s * Y1S + c] = lut6_wd(we1, dd1, b);
    }
    __syncthreads();

    // ---- Layer 2: 16 x 4 = 64 tasks ----
    if (tid < SPB * L2) {
        const int s = tid & 15;
        const int c = tid >> 4;
        float we2[32], dd2[32];
        load_row_wd(&wq2[c * 64], we2, dd2);
        float b[6];
#pragma unroll
        for (int j = 0; j < 6; ++j) b[j] = y1[s * Y1S + c * 6 + j];
        y2[s * Y2S + c] = lut6_wd(we2, dd2, b);
    }
    __syncthreads();

    // ---- Layer 3: one thread per sample ----
    if (tid < SPB) {
        const int s = tid;
        float we3[32], dd3[32];
        load_row_wd(wq3, we3, dd3);
        float b[6];
#pragma unroll
        for (int j = 0; j < 6; ++j) b[j] = y2[s * Y2S + j];
        out[(size_t)(sh * SPB + s) * O_NUM + o] = lut6_wd(we3, dd3, b);
    }
}

extern "C" void kernel_launch(void* const* d_in, const int* in_sizes, int n_in,
                              void* d_out, int out_size, void* d_ws, size_t ws_size,
                              hipStream_t stream) {
    const float* x  = (const float*)d_in[0];
    const float* w0 = (const float*)d_in[1];
    const float* w1 = (const float*)d_in[2];
    const float* w2 = (const float*)d_in[3];
    const float* w3 = (const float*)d_in[4];
    float* out = (float*)d_out;

    lut_quant_fc_kernel<<<dim3(O_NUM * 2), dim3(512), 0, stream>>>(x, w0, w1, w2, w3, out);
}